// Round 2
// baseline (7601.896 us; speedup 1.0000x reference)
//
#include <hip/hip_runtime.h>

#define DCOND 48
#define KBINS 24
#define HID 128
#define TSTEPS 10
#define NPAR 73          // 3*K + 1
#define TAILF 15.0f
#define BLK 256

__device__ __forceinline__ float silu_f(float v) {
    // v * sigmoid(v) = v / (1 + e^-v); fast div + fast exp (rel err ~2^-20, fine vs 2% threshold)
    return __fdividef(v, 1.0f + __expf(-v));
}

// Compute NOUT (multiple of 8) outputs [j0, j0+NOUT) of a dense layer for this
// thread's sample. Inputs hin[KIN] in registers (k-loop fully unrolled), weights
// row-stride WS read via uniform scalar loads (s_load_dwordx8 expected), outputs
// bounced into per-thread LDS column sb[(jj)*BLK + tid] (2-way bank alias = free,
// owner-thread-only => no barriers anywhere in this kernel).
template<int KIN, int WS, int NOUT, bool ACT>
__device__ __forceinline__ void dense_chunk(const float* __restrict__ W,
                                            const float* __restrict__ bias,
                                            int j0,
                                            const float (&hin)[KIN],
                                            float* __restrict__ sb,
                                            int tid)
{
    #pragma unroll 1
    for (int jj = 0; jj < NOUT; jj += 8) {
        const int j = j0 + jj;
        float a[8];
        #pragma unroll
        for (int u = 0; u < 8; ++u) a[u] = bias[j + u];
        #pragma unroll
        for (int k = 0; k < KIN; ++k) {
            const float* w = W + k * WS + j;   // uniform address -> scalar loads
            const float hk = hin[k];
            #pragma unroll
            for (int u = 0; u < 8; ++u) a[u] = fmaf(hk, w[u], a[u]);
        }
        #pragma unroll
        for (int u = 0; u < 8; ++u) {
            float v = ACT ? silu_f(a[u]) : a[u];
            sb[(jj + u) * BLK + tid] = v;
        }
    }
}

__global__ __launch_bounds__(BLK, 2)
void nsf_fwd(const float* __restrict__ z_g, const float* __restrict__ ctx_g,
             const float* __restrict__ W0g, const float* __restrict__ b0g,
             const float* __restrict__ W1g, const float* __restrict__ b1g,
             const float* __restrict__ W2g, const float* __restrict__ b2g,
             const float* __restrict__ W3g, const float* __restrict__ b3g,
             const float* __restrict__ locp, const float* __restrict__ sclp,
             float* __restrict__ out, int B)
{
    __shared__ float sbuf[64 * BLK];   // 64 KB: per-thread column bounce buffer
    const int tid = threadIdx.x;
    const int gid = blockIdx.x * BLK + tid;
    if (gid >= B) return;

    float x  = z_g[gid];
    float ld = 0.0f;

    #pragma unroll 1
    for (int t = 0; t < TSTEPS; ++t) {
        // stop LICM from hoisting the context loads across all 10 steps
        // (would add +48 persistent VGPRs and spill under the 256-reg cap)
        asm volatile("" ::: "memory");

        const float* W0 = W0g + (size_t)t * DCOND * HID;
        const float* b0 = b0g + (size_t)t * HID;
        const float* W1 = W1g + (size_t)t * HID * HID;
        const float* b1 = b1g + (size_t)t * HID;
        const float* W2 = W2g + (size_t)t * HID * HID;
        const float* b2 = b2g + (size_t)t * HID;
        const float* W3 = W3g + (size_t)t * HID * NPAR;
        const float* b3 = b3g + (size_t)t * NPAR;

        // context row -> registers (L3-resident after step 0)
        float ctx[DCOND];
        #pragma unroll
        for (int k = 0; k < DCOND; ++k) ctx[k] = ctx_g[(size_t)gid * DCOND + k];

        float h[HID];

        // ---- layer 0: 48 -> 128, silu
        dense_chunk<DCOND, HID, 64, true>(W0, b0, 0, ctx, sbuf, tid);
        #pragma unroll
        for (int j = 0; j < 64; ++j) h[j] = sbuf[j * BLK + tid];
        dense_chunk<DCOND, HID, 64, true>(W0, b0, 64, ctx, sbuf, tid);
        #pragma unroll
        for (int j = 0; j < 64; ++j) h[64 + j] = sbuf[j * BLK + tid];

        // ---- layers 1 & 2: 128 -> 128, silu
        #pragma unroll 1
        for (int l = 0; l < 2; ++l) {
            const float* W  = (l == 0) ? W1 : W2;
            const float* bb = (l == 0) ? b1 : b2;
            float hlo[64];
            dense_chunk<HID, HID, 64, true>(W, bb, 0, h, sbuf, tid);
            #pragma unroll
            for (int j = 0; j < 64; ++j) hlo[j] = sbuf[j * BLK + tid];
            dense_chunk<HID, HID, 64, true>(W, bb, 64, h, sbuf, tid);
            #pragma unroll
            for (int j = 0; j < 64; ++j) h[64 + j] = sbuf[j * BLK + tid];
            #pragma unroll
            for (int j = 0; j < 64; ++j) h[j] = hlo[j];
        }

        // ---- layer 3: 128 -> 73 (raw params)
        float p[NPAR];
        dense_chunk<HID, NPAR, 64, false>(W3, b3, 0, h, sbuf, tid);
        #pragma unroll
        for (int j = 0; j < 64; ++j) p[j] = sbuf[j * BLK + tid];
        dense_chunk<HID, NPAR, 8, false>(W3, b3, 64, h, sbuf, tid);
        #pragma unroll
        for (int j = 0; j < 8; ++j) p[64 + j] = sbuf[j * BLK + tid];
        {   // tail column 72 (kept separate so the x8 chunks never read OOB)
            float a = b3[72];
            #pragma unroll
            for (int k = 0; k < HID; ++k) a = fmaf(h[k], W3[k * NPAR + 72], a);
            p[72] = a;
        }

        // ---- rational-quadratic spline (all register-resident, loops unrolled)
        float mw = p[0];
        #pragma unroll
        for (int i = 1; i < KBINS; ++i) mw = fmaxf(mw, p[i]);
        float we[KBINS]; float wsum = 0.0f;
        #pragma unroll
        for (int i = 0; i < KBINS; ++i) { we[i] = __expf(p[i] - mw); wsum += we[i]; }
        const float wmul = __fdividef(2.0f * TAILF, wsum);

        float mh = p[KBINS];
        #pragma unroll
        for (int i = 1; i < KBINS; ++i) mh = fmaxf(mh, p[KBINS + i]);
        float he[KBINS]; float hsum = 0.0f;
        #pragma unroll
        for (int i = 0; i < KBINS; ++i) { he[i] = __expf(p[KBINS + i] - mh); hsum += he[i]; }
        const float hmul = __fdividef(2.0f * TAILF, hsum);

        float dv[KBINS + 1];
        #pragma unroll
        for (int i = 0; i <= KBINS; ++i) {
            float xd = p[2 * KBINS + i];
            // stable softplus + 0.001
            dv[i] = fmaxf(xd, 0.0f) + __logf(1.0f + __expf(-fabsf(xd))) + 0.001f;
        }

        // ---- fused bin search + gather, matching REFERENCE semantics exactly:
        // cw = pad(cumsum(widths), front=-TAIL):  cw[0] = -TAIL,
        //                                         cw[i] = sum(widths[:i])  (i>=1, RAW cumsum!)
        // idx = clip(#{i in 1..K : cw[i] < x}, 0, K-1)
        // (loop over i=1..K-1 selecting the last hit subsumes the clip)
        float cw = 0.0f, ch = 0.0f;        // raw running cumsums (reference, no -TAIL shift)
        float cwk = -TAILF, chk = -TAILF;  // idx = 0 default: cw[0] = ch[0] = -TAIL
        float wk = we[0] * wmul, hk = he[0] * hmul, dk = dv[0], dk1 = dv[1];
        #pragma unroll
        for (int i = 1; i < KBINS; ++i) {
            cw += we[i - 1] * wmul;        // cw[i]
            ch += he[i - 1] * hmul;        // ch[i]
            if (cw < x) {
                cwk = cw; chk = ch;
                wk = we[i] * wmul; hk = he[i] * hmul;
                dk = dv[i]; dk1 = dv[i + 1];
            }
        }

        const bool inside = (x >= -TAILF) && (x <= TAILF);
        const float sr = __fdividef(hk, wk);
        float xi = __fdividef(x - cwk, wk);
        xi = fminf(fmaxf(xi, 1e-6f), 1.0f - 1e-6f);
        const float om  = 1.0f - xi;
        const float xio = xi * om;
        const float numer = hk * (sr * xi * xi + dk * xio);
        const float denom = sr + (dk + dk1 - 2.0f * sr) * xio;
        const float y = chk + __fdividef(numer, denom);
        const float dyd = __fdividef(sr * sr * (dk1 * xi * xi + 2.0f * sr * xio + dk * om * om),
                                     denom * denom);
        const float lg = __logf(fmaxf(dyd, 1e-10f)) + __logf(fmaxf(hk, 1e-10f))
                       - __logf(fmaxf(wk, 1e-10f));
        x  = inside ? y : x;
        ld += inside ? lg : 0.0f;
    }

    const float s = fmaxf(sclp[0], 0.1f);
    out[gid]     = fmaf(x, s, locp[0]);
    out[B + gid] = ld;
}

extern "C" void kernel_launch(void* const* d_in, const int* in_sizes, int n_in,
                              void* d_out, int out_size, void* d_ws, size_t ws_size,
                              hipStream_t stream) {
    const float* z    = (const float*)d_in[0];
    const float* ctx  = (const float*)d_in[1];
    const float* W0   = (const float*)d_in[2];
    const float* b0   = (const float*)d_in[3];
    const float* W1   = (const float*)d_in[4];
    const float* b1   = (const float*)d_in[5];
    const float* W2   = (const float*)d_in[6];
    const float* b2   = (const float*)d_in[7];
    const float* W3   = (const float*)d_in[8];
    const float* b3   = (const float*)d_in[9];
    const float* loc  = (const float*)d_in[10];
    const float* scl  = (const float*)d_in[11];
    float* out = (float*)d_out;

    const int B = in_sizes[0];
    const int nblk = (B + BLK - 1) / BLK;   // 512 for B=131072

    hipLaunchKernelGGL(nsf_fwd, dim3(nblk), dim3(BLK), 0, stream,
                       z, ctx, W0, b0, W1, b1, W2, b2, W3, b3, loc, scl, out, B);
}

// Round 3
// 642.719 us; speedup vs baseline: 11.8277x; 11.8277x over previous
//
#include <hip/hip_runtime.h>
#include <hip/hip_bf16.h>

#define DCOND 48
#define KBINS 24
#define HID 128
#define TSTEPS 10
#define NPAR 73          // 3*K + 1
#define TAILF 15.0f

typedef __attribute__((ext_vector_type(8))) short v8s;   // 8 bf16 (4 VGPR) MFMA frag
typedef __attribute__((ext_vector_type(4))) float f32x4;

__device__ __forceinline__ short f2bf(float f) {
    __hip_bfloat16 h = __float2bfloat16(f);              // RNE
    return __builtin_bit_cast(short, h);
}
__device__ __forceinline__ float bf2f(short s) {
    unsigned u = ((unsigned)(unsigned short)s) << 16;
    return __builtin_bit_cast(float, u);
}
__device__ __forceinline__ float silu_f(float v) {
    return __fdividef(v, 1.0f + __expf(-v));
}

// ===========================================================================
// Weight prep: fp32 W -> frag-ordered bf16 hi/lo planes in d_ws.
// Per step (shorts): L0 hi@0 lo@8192 | L1 hi@16384 lo@32768 | L2 hi@49152
// lo@65536 | L3 hi@81920 lo@92160.  Step stride 102400 shorts.
// Element e of a layer: e = ((kc*NT + nt)*64 + lane)*8 + j ;
//   k = kc*32 + (lane>>4)*8 + j , n = nt*16 + (lane&15); zero-padded.
// ===========================================================================
__global__ void prep_w(const float* __restrict__ W0, const float* __restrict__ W1,
                       const float* __restrict__ W2, const float* __restrict__ W3,
                       short* __restrict__ ws)
{
    int g = blockIdx.x * 256 + threadIdx.x;
    if (g >= TSTEPS * 51200) return;
    int t = g / 51200;
    int r = g % 51200;

    int base_e, elems, NT, Kreal, Nreal;
    const float* W;
    if (r < 8192)       { base_e = 0;     elems = 8192;  NT = 8; Kreal = 48;  Nreal = 128; W = W0 + (size_t)t * DCOND * HID; }
    else if (r < 24576) { base_e = 8192;  elems = 16384; NT = 8; Kreal = 128; Nreal = 128; W = W1 + (size_t)t * HID * HID; }
    else if (r < 40960) { base_e = 24576; elems = 16384; NT = 8; Kreal = 128; Nreal = 128; W = W2 + (size_t)t * HID * HID; }
    else                { base_e = 40960; elems = 10240; NT = 5; Kreal = 128; Nreal = 73;  W = W3 + (size_t)t * HID * NPAR; }

    int e  = r - base_e;
    int j  = e & 7;
    int ln = (e >> 3) & 63;
    int q  = e >> 9;               // kc*NT + nt
    int nt = q % NT, kc = q / NT;
    int k  = kc * 32 + (ln >> 4) * 8 + j;
    int n  = nt * 16 + (ln & 15);

    float v = 0.0f;
    if (k < Kreal && n < Nreal) v = W[(size_t)k * Nreal + n];
    short hi = f2bf(v);
    short lo = f2bf(v - bf2f(hi));

    size_t o = (size_t)t * 102400 + 2 * (size_t)base_e + e;
    ws[o]         = hi;
    ws[o + elems] = lo;
}

// ===========================================================================
// Main fused kernel: 128 samples/block, 512 threads (8 waves, 1 m-tile each).
// H: fp32 [128][128] LDS, 16B XOR swizzle. W: bf16 hi|lo LDS, frag-linear.
// ===========================================================================
#define MBLK 128
#define NTHR 512

__device__ __forceinline__ void w_write_chunk(short* dst, const short* src) {
    *(v8s*)dst = *(const v8s*)src;
}

template<int ROUNDS>
__device__ __forceinline__ void w_issue(const short* __restrict__ g, int tid, v8s (&r)[8]) {
    #pragma unroll
    for (int i = 0; i < ROUNDS; ++i)
        r[i] = *(const v8s*)(g + tid * 8 + i * 4096);
}
template<int ROUNDS>
__device__ __forceinline__ void w_flush(short* __restrict__ lds, int tid, const v8s (&r)[8]) {
    #pragma unroll
    for (int i = 0; i < ROUNDS; ++i)
        *(v8s*)(lds + tid * 8 + i * 4096) = r[i];
}

template<int KC, int NT, bool ACT>
__device__ __forceinline__ void layer_run(const float* __restrict__ bias, int nreal,
                                          float* __restrict__ Hlds,
                                          const short* __restrict__ Wlds,
                                          int lane, int wave)
{
    constexpr int ELEMS = KC * NT * 512;
    const int arow = wave * 16 + (lane & 15);
    const int asw  = (arow & 7) << 4;
    const int kgrp = (lane >> 4) * 8;

    // A-frags: read own rows (fp32), split into bf16 hi/lo
    v8s ah[KC], al[KC];
    #pragma unroll
    for (int kc = 0; kc < KC; ++kc) {
        const int kb4 = (kc * 32 + kgrp) * 4;
        f32x4 a0 = *(const f32x4*)((const char*)Hlds + arow * 512 + (kb4 ^ asw));
        f32x4 a1 = *(const f32x4*)((const char*)Hlds + arow * 512 + ((kb4 + 16) ^ asw));
        #pragma unroll
        for (int u = 0; u < 4; ++u) {
            short h0 = f2bf(a0[u]); ah[kc][u]     = h0; al[kc][u]     = f2bf(a0[u] - bf2f(h0));
            short h1 = f2bf(a1[u]); ah[kc][4 + u] = h1; al[kc][4 + u] = f2bf(a1[u] - bf2f(h1));
        }
    }

    const int crow0 = wave * 16 + (lane >> 4) * 4;
    const int ncol  = lane & 15;

    // paired n-tiles: two independent accumulator chains
    #pragma unroll
    for (int np = 0; np < NT / 2; ++np) {
        const int nt0 = np * 2, nt1 = np * 2 + 1;
        const int n0 = nt0 * 16 + ncol, n1 = nt1 * 16 + ncol;
        const float bv0 = (n0 < nreal) ? bias[n0] : 0.0f;
        const float bv1 = (n1 < nreal) ? bias[n1] : 0.0f;
        f32x4 acc0 = {bv0, bv0, bv0, bv0};
        f32x4 acc1 = {bv1, bv1, bv1, bv1};
        #pragma unroll
        for (int kc = 0; kc < KC; ++kc) {
            const short* bp0 = Wlds + ((size_t)(kc * NT + nt0) * 64 + lane) * 8;
            const short* bp1 = Wlds + ((size_t)(kc * NT + nt1) * 64 + lane) * 8;
            v8s bh0 = *(const v8s*)bp0;
            v8s bl0 = *(const v8s*)(bp0 + ELEMS);
            v8s bh1 = *(const v8s*)bp1;
            v8s bl1 = *(const v8s*)(bp1 + ELEMS);
            acc0 = __builtin_amdgcn_mfma_f32_16x16x32_bf16(ah[kc], bh0, acc0, 0, 0, 0);
            acc1 = __builtin_amdgcn_mfma_f32_16x16x32_bf16(ah[kc], bh1, acc1, 0, 0, 0);
            acc0 = __builtin_amdgcn_mfma_f32_16x16x32_bf16(ah[kc], bl0, acc0, 0, 0, 0);
            acc1 = __builtin_amdgcn_mfma_f32_16x16x32_bf16(ah[kc], bl1, acc1, 0, 0, 0);
            acc0 = __builtin_amdgcn_mfma_f32_16x16x32_bf16(al[kc], bh0, acc0, 0, 0, 0);
            acc1 = __builtin_amdgcn_mfma_f32_16x16x32_bf16(al[kc], bh1, acc1, 0, 0, 0);
        }
        #pragma unroll
        for (int r = 0; r < 4; ++r) {
            const int row = crow0 + r;
            const int sw  = (row & 7) << 4;
            float v0 = acc0[r], v1 = acc1[r];
            if (ACT) { v0 = silu_f(v0); v1 = silu_f(v1); }
            *(float*)((char*)Hlds + row * 512 + ((n0 * 4) ^ sw)) = v0;
            *(float*)((char*)Hlds + row * 512 + ((n1 * 4) ^ sw)) = v1;
        }
    }
    if (NT & 1) {   // odd tail (layer 3: NT=5)
        const int nt = NT - 1;
        const int n0 = nt * 16 + ncol;
        const float bv0 = (n0 < nreal) ? bias[n0] : 0.0f;
        f32x4 acc0 = {bv0, bv0, bv0, bv0};
        #pragma unroll
        for (int kc = 0; kc < KC; ++kc) {
            const short* bp0 = Wlds + ((size_t)(kc * NT + nt) * 64 + lane) * 8;
            v8s bh0 = *(const v8s*)bp0;
            v8s bl0 = *(const v8s*)(bp0 + ELEMS);
            acc0 = __builtin_amdgcn_mfma_f32_16x16x32_bf16(ah[kc], bh0, acc0, 0, 0, 0);
            acc0 = __builtin_amdgcn_mfma_f32_16x16x32_bf16(ah[kc], bl0, acc0, 0, 0, 0);
            acc0 = __builtin_amdgcn_mfma_f32_16x16x32_bf16(al[kc], bh0, acc0, 0, 0, 0);
        }
        #pragma unroll
        for (int r = 0; r < 4; ++r) {
            const int row = crow0 + r;
            const int sw  = (row & 7) << 4;
            float v0 = acc0[r];
            if (ACT) v0 = silu_f(v0);
            *(float*)((char*)Hlds + row * 512 + ((n0 * 4) ^ sw)) = v0;
        }
    }
}

__global__ __launch_bounds__(NTHR, 1)
void nsf_mfma(const float* __restrict__ z_g, const float* __restrict__ ctx_g,
              const float* __restrict__ b0g, const float* __restrict__ b1g,
              const float* __restrict__ b2g, const float* __restrict__ b3g,
              const float* __restrict__ locp, const float* __restrict__ sclp,
              const short* __restrict__ wsW, float* __restrict__ out, int B)
{
    __shared__ float Hlds[MBLK * 128];   // 64 KB, swizzled
    __shared__ short Wlds[32768];        // 64 KB: [hi(elems) | lo(elems)]
    const int tid  = threadIdx.x;
    const int lane = tid & 63, wave = tid >> 6;
    const int blk  = blockIdx.x;

    float x = 0.0f, ld = 0.0f;
    if (tid < MBLK) {
        int gid = blk * MBLK + tid;
        if (gid > B - 1) gid = B - 1;
        x = z_g[gid];
    }

    v8s wreg[8];

    #pragma unroll 1
    for (int t = 0; t < TSTEPS; ++t) {
        const short* wstep = wsW + (size_t)t * 102400;

        // issue L0 weight loads early (in flight under ctx staging)
        w_issue<4>(wstep, tid, wreg);

        // stage ctx -> H (wave-local rows: thread tid writes row tid>>2,
        // which belongs to wave tid>>6's m-tile -> no barrier needed vs A-reads)
        {
            const int row = tid >> 2, q = tid & 3;
            int gs = blk * MBLK + row;
            if (gs > B - 1) gs = B - 1;
            const float* cg = ctx_g + (size_t)gs * DCOND + q * 12;
            f32x4 c0 = *(const f32x4*)cg;
            f32x4 c1 = *(const f32x4*)(cg + 4);
            f32x4 c2 = *(const f32x4*)(cg + 8);
            const int sw = (row & 7) << 4;
            char* hb = (char*)Hlds + row * 512;
            *(f32x4*)(hb + ((q * 48)      ^ sw)) = c0;
            *(f32x4*)(hb + ((q * 48 + 16) ^ sw)) = c1;
            *(f32x4*)(hb + ((q * 48 + 32) ^ sw)) = c2;
            f32x4 zz = {0, 0, 0, 0};
            *(f32x4*)(hb + ((192 + q * 16) ^ sw)) = zz;   // zero-pad k=48..63
        }

        w_flush<4>(Wlds, tid, wreg);          // prev L3 readers long done (barriers 9,10)
        w_issue<8>(wstep + 16384, tid, wreg); // L1 in flight under L0 compute
        __syncthreads();                      // W(L0) + ctx visible

        layer_run<2, 8, true>(b0g + t * HID, HID, Hlds, Wlds, lane, wave);
        __syncthreads();                      // all L0 W-reads done

        w_flush<8>(Wlds, tid, wreg);
        w_issue<8>(wstep + 49152, tid, wreg); // L2 in flight
        __syncthreads();

        layer_run<4, 8, true>(b1g + t * HID, HID, Hlds, Wlds, lane, wave);
        __syncthreads();

        w_flush<8>(Wlds, tid, wreg);
        w_issue<5>(wstep + 81920, tid, wreg); // L3 in flight
        __syncthreads();

        layer_run<4, 8, true>(b2g + t * HID, HID, Hlds, Wlds, lane, wave);
        __syncthreads();

        w_flush<5>(Wlds, tid, wreg);
        __syncthreads();

        layer_run<4, 5, false>(b3g + t * NPAR, NPAR, Hlds, Wlds, lane, wave);
        __syncthreads();                      // params visible to spline threads

        // ---- spline: threads 0..127, one sample each (params via swizzled LDS)
        if (tid < MBLK) {
            const char* hrow = (const char*)Hlds + tid * 512;
            const int sw = (tid & 7) << 4;

            float pw[KBINS];
            #pragma unroll
            for (int i = 0; i < KBINS; ++i) pw[i] = *(const float*)(hrow + ((i * 4) ^ sw));
            float mw = pw[0];
            #pragma unroll
            for (int i = 1; i < KBINS; ++i) mw = fmaxf(mw, pw[i]);
            float wsum = 0.0f;
            #pragma unroll
            for (int i = 0; i < KBINS; ++i) { pw[i] = __expf(pw[i] - mw); wsum += pw[i]; }
            const float wmul = __fdividef(2.0f * TAILF, wsum);

            float ph[KBINS];
            #pragma unroll
            for (int i = 0; i < KBINS; ++i) ph[i] = *(const float*)(hrow + (((KBINS + i) * 4) ^ sw));
            float mh = ph[0];
            #pragma unroll
            for (int i = 1; i < KBINS; ++i) mh = fmaxf(mh, ph[i]);
            float hsum = 0.0f;
            #pragma unroll
            for (int i = 0; i < KBINS; ++i) { ph[i] = __expf(ph[i] - mh); hsum += ph[i]; }
            const float hmul = __fdividef(2.0f * TAILF, hsum);

            float dv[KBINS + 1];
            #pragma unroll
            for (int i = 0; i <= KBINS; ++i) {
                float xd = *(const float*)(hrow + (((2 * KBINS + i) * 4) ^ sw));
                dv[i] = fmaxf(xd, 0.0f) + __logf(1.0f + __expf(-fabsf(xd))) + 0.001f;
            }

            // reference semantics: cw[0]=-TAIL, cw[i>=1]=RAW cumsum (no shift)
            float cw = 0.0f, ch = 0.0f;
            float cwk = -TAILF, chk = -TAILF;
            float wk = pw[0] * wmul, hk = ph[0] * hmul, dk = dv[0], dk1 = dv[1];
            #pragma unroll
            for (int i = 1; i < KBINS; ++i) {
                cw += pw[i - 1] * wmul;
                ch += ph[i - 1] * hmul;
                if (cw < x) {
                    cwk = cw; chk = ch;
                    wk = pw[i] * wmul; hk = ph[i] * hmul;
                    dk = dv[i]; dk1 = dv[i + 1];
                }
            }

            const bool inside = (x >= -TAILF) && (x <= TAILF);
            const float sr = __fdividef(hk, wk);
            float xi = __fdividef(x - cwk, wk);
            xi = fminf(fmaxf(xi, 1e-6f), 1.0f - 1e-6f);
            const float om  = 1.0f - xi;
            const float xio = xi * om;
            const float numer = hk * (sr * xi * xi + dk * xio);
            const float denom = sr + (dk + dk1 - 2.0f * sr) * xio;
            const float y = chk + __fdividef(numer, denom);
            const float dyd = __fdividef(sr * sr * (dk1 * xi * xi + 2.0f * sr * xio + dk * om * om),
                                         denom * denom);
            const float lg = __logf(fmaxf(dyd, 1e-10f)) + __logf(fmaxf(hk, 1e-10f))
                           - __logf(fmaxf(wk, 1e-10f));
            x  = inside ? y : x;
            ld += inside ? lg : 0.0f;
        }
        __syncthreads();   // spline H-reads done before next step's ctx restage
    }

    if (tid < MBLK) {
        const int gid = blk * MBLK + tid;
        if (gid < B) {
            const float s = fmaxf(sclp[0], 0.1f);
            out[gid]     = fmaf(x, s, locp[0]);
            out[B + gid] = ld;
        }
    }
}

// ===========================================================================
// Fallback (proven round-2 fp32 kernel) if ws is too small for weight prep
// ===========================================================================
#define FBLK 256
template<int KIN, int WS, int NOUT, bool ACT>
__device__ __forceinline__ void dense_chunk(const float* __restrict__ W,
                                            const float* __restrict__ bias,
                                            int j0, const float (&hin)[KIN],
                                            float* __restrict__ sb, int tid)
{
    #pragma unroll 1
    for (int jj = 0; jj < NOUT; jj += 8) {
        const int j = j0 + jj;
        float a[8];
        #pragma unroll
        for (int u = 0; u < 8; ++u) a[u] = bias[j + u];
        #pragma unroll
        for (int k = 0; k < KIN; ++k) {
            const float* w = W + k * WS + j;
            const float hk = hin[k];
            #pragma unroll
            for (int u = 0; u < 8; ++u) a[u] = fmaf(hk, w[u], a[u]);
        }
        #pragma unroll
        for (int u = 0; u < 8; ++u) {
            float v = ACT ? silu_f(a[u]) : a[u];
            sb[(jj + u) * FBLK + tid] = v;
        }
    }
}

__global__ __launch_bounds__(FBLK, 2)
void nsf_fwd_slow(const float* __restrict__ z_g, const float* __restrict__ ctx_g,
                  const float* __restrict__ W0g, const float* __restrict__ b0g,
                  const float* __restrict__ W1g, const float* __restrict__ b1g,
                  const float* __restrict__ W2g, const float* __restrict__ b2g,
                  const float* __restrict__ W3g, const float* __restrict__ b3g,
                  const float* __restrict__ locp, const float* __restrict__ sclp,
                  float* __restrict__ out, int B)
{
    __shared__ float sbuf[64 * FBLK];
    const int tid = threadIdx.x;
    const int gid = blockIdx.x * FBLK + tid;
    if (gid >= B) return;
    float x = z_g[gid], ld = 0.0f;
    #pragma unroll 1
    for (int t = 0; t < TSTEPS; ++t) {
        asm volatile("" ::: "memory");
        const float* W0 = W0g + (size_t)t * DCOND * HID;
        const float* b0 = b0g + (size_t)t * HID;
        const float* W1 = W1g + (size_t)t * HID * HID;
        const float* b1 = b1g + (size_t)t * HID;
        const float* W2 = W2g + (size_t)t * HID * HID;
        const float* b2 = b2g + (size_t)t * HID;
        const float* W3 = W3g + (size_t)t * HID * NPAR;
        const float* b3 = b3g + (size_t)t * NPAR;
        float ctx[DCOND];
        #pragma unroll
        for (int k = 0; k < DCOND; ++k) ctx[k] = ctx_g[(size_t)gid * DCOND + k];
        float h[HID];
        dense_chunk<DCOND, HID, 64, true>(W0, b0, 0, ctx, sbuf, tid);
        #pragma unroll
        for (int j = 0; j < 64; ++j) h[j] = sbuf[j * FBLK + tid];
        dense_chunk<DCOND, HID, 64, true>(W0, b0, 64, ctx, sbuf, tid);
        #pragma unroll
        for (int j = 0; j < 64; ++j) h[64 + j] = sbuf[j * FBLK + tid];
        #pragma unroll 1
        for (int l = 0; l < 2; ++l) {
            const float* W  = (l == 0) ? W1 : W2;
            const float* bb = (l == 0) ? b1 : b2;
            float hlo[64];
            dense_chunk<HID, HID, 64, true>(W, bb, 0, h, sbuf, tid);
            #pragma unroll
            for (int j = 0; j < 64; ++j) hlo[j] = sbuf[j * FBLK + tid];
            dense_chunk<HID, HID, 64, true>(W, bb, 64, h, sbuf, tid);
            #pragma unroll
            for (int j = 0; j < 64; ++j) h[64 + j] = sbuf[j * FBLK + tid];
            #pragma unroll
            for (int j = 0; j < 64; ++j) h[j] = hlo[j];
        }
        float p[NPAR];
        dense_chunk<HID, NPAR, 64, false>(W3, b3, 0, h, sbuf, tid);
        #pragma unroll
        for (int j = 0; j < 64; ++j) p[j] = sbuf[j * FBLK + tid];
        dense_chunk<HID, NPAR, 8, false>(W3, b3, 64, h, sbuf, tid);
        #pragma unroll
        for (int j = 0; j < 8; ++j) p[64 + j] = sbuf[j * FBLK + tid];
        {
            float a = b3[72];
            #pragma unroll
            for (int k = 0; k < HID; ++k) a = fmaf(h[k], W3[k * NPAR + 72], a);
            p[72] = a;
        }
        float mw = p[0];
        #pragma unroll
        for (int i = 1; i < KBINS; ++i) mw = fmaxf(mw, p[i]);
        float we[KBINS]; float wsum = 0.0f;
        #pragma unroll
        for (int i = 0; i < KBINS; ++i) { we[i] = __expf(p[i] - mw); wsum += we[i]; }
        const float wmul = __fdividef(2.0f * TAILF, wsum);
        float mh = p[KBINS];
        #pragma unroll
        for (int i = 1; i < KBINS; ++i) mh = fmaxf(mh, p[KBINS + i]);
        float he[KBINS]; float hsum = 0.0f;
        #pragma unroll
        for (int i = 0; i < KBINS; ++i) { he[i] = __expf(p[KBINS + i] - mh); hsum += he[i]; }
        const float hmul = __fdividef(2.0f * TAILF, hsum);
        float dvv[KBINS + 1];
        #pragma unroll
        for (int i = 0; i <= KBINS; ++i) {
            float xd = p[2 * KBINS + i];
            dvv[i] = fmaxf(xd, 0.0f) + __logf(1.0f + __expf(-fabsf(xd))) + 0.001f;
        }
        float cw = 0.0f, ch = 0.0f, cwk = -TAILF, chk = -TAILF;
        float wk = we[0] * wmul, hk = he[0] * hmul, dk = dvv[0], dk1 = dvv[1];
        #pragma unroll
        for (int i = 1; i < KBINS; ++i) {
            cw += we[i - 1] * wmul;
            ch += he[i - 1] * hmul;
            if (cw < x) {
                cwk = cw; chk = ch;
                wk = we[i] * wmul; hk = he[i] * hmul;
                dk = dvv[i]; dk1 = dvv[i + 1];
            }
        }
        const bool inside = (x >= -TAILF) && (x <= TAILF);
        const float sr = __fdividef(hk, wk);
        float xi = __fdividef(x - cwk, wk);
        xi = fminf(fmaxf(xi, 1e-6f), 1.0f - 1e-6f);
        const float om  = 1.0f - xi;
        const float xio = xi * om;
        const float numer = hk * (sr * xi * xi + dk * xio);
        const float denom = sr + (dk + dk1 - 2.0f * sr) * xio;
        const float y = chk + __fdividef(numer, denom);
        const float dyd = __fdividef(sr * sr * (dk1 * xi * xi + 2.0f * sr * xio + dk * om * om),
                                     denom * denom);
        const float lg = __logf(fmaxf(dyd, 1e-10f)) + __logf(fmaxf(hk, 1e-10f))
                       - __logf(fmaxf(wk, 1e-10f));
        x  = inside ? y : x;
        ld += inside ? lg : 0.0f;
    }
    const float s = fmaxf(sclp[0], 0.1f);
    out[gid]     = fmaf(x, s, locp[0]);
    out[B + gid] = ld;
}

// ===========================================================================
extern "C" void kernel_launch(void* const* d_in, const int* in_sizes, int n_in,
                              void* d_out, int out_size, void* d_ws, size_t ws_size,
                              hipStream_t stream) {
    const float* z    = (const float*)d_in[0];
    const float* ctx  = (const float*)d_in[1];
    const float* W0   = (const float*)d_in[2];
    const float* b0   = (const float*)d_in[3];
    const float* W1   = (const float*)d_in[4];
    const float* b1   = (const float*)d_in[5];
    const float* W2   = (const float*)d_in[6];
    const float* b2   = (const float*)d_in[7];
    const float* W3   = (const float*)d_in[8];
    const float* b3   = (const float*)d_in[9];
    const float* loc  = (const float*)d_in[10];
    const float* scl  = (const float*)d_in[11];
    float* out = (float*)d_out;
    const int B = in_sizes[0];

    const size_t ws_need = (size_t)TSTEPS * 102400 * sizeof(short);   // 2,048,000 B
    if (ws_size < ws_need) {
        const int nblk = (B + FBLK - 1) / FBLK;
        hipLaunchKernelGGL(nsf_fwd_slow, dim3(nblk), dim3(FBLK), 0, stream,
                           z, ctx, W0, b0, W1, b1, W2, b2, W3, b3, loc, scl, out, B);
        return;
    }

    short* ws = (short*)d_ws;
    const int prep_total = TSTEPS * 51200;
    hipLaunchKernelGGL(prep_w, dim3((prep_total + 255) / 256), dim3(256), 0, stream,
                       W0, W1, W2, W3, ws);

    const int nblk = (B + MBLK - 1) / MBLK;
    hipLaunchKernelGGL(nsf_mfma, dim3(nblk), dim3(NTHR), 0, stream,
                       z, ctx, b0, b1, b2, b3, loc, scl, ws, out, B);
}

// Round 5
// 627.706 us; speedup vs baseline: 12.1106x; 1.0239x over previous
//
#include <hip/hip_runtime.h>
#include <hip/hip_bf16.h>

#define DCOND 48
#define KBINS 24
#define HID 128
#define TSTEPS 10
#define NPAR 73          // 3*K + 1
#define TAILF 15.0f

typedef __attribute__((ext_vector_type(8))) short v8s;   // 8 bf16 = one MFMA frag
typedef __attribute__((ext_vector_type(4))) float f32x4;
typedef __attribute__((ext_vector_type(4))) unsigned u32x4;

__device__ __forceinline__ short f2bf(float f) {
    __hip_bfloat16 h = __float2bfloat16(f);              // RNE (prep kernel only)
    return __builtin_bit_cast(short, h);
}
__device__ __forceinline__ float bf2f(short s) {
    unsigned u = ((unsigned)(unsigned short)s) << 16;
    return __builtin_bit_cast(float, u);
}
__device__ __forceinline__ float silu_f(float v) {
    return __fdividef(v, 1.0f + __expf(-v));
}

// HW packed fp32->2xbf16 (RNE). No builtin on gfx950 (learn_hip m240) -> asm.
__device__ __forceinline__ unsigned cvt_pk(float a, float b) {
    unsigned r;
    asm("v_cvt_pk_bf16_f32 %0, %1, %2" : "=v"(r) : "v"(a), "v"(b));
    return r;   // low16 = bf16(a), high16 = bf16(b)
}

// 8 fp32 -> bf16 hi-frag + bf16 lo-frag (hi RNE, lo = RNE(x - hi)).
// 4 cvt_pk + 8 shifts/ands + 8 subs + 4 cvt_pk = 24 VALU per 8 elems.
__device__ __forceinline__ void split8(f32x4 a0, f32x4 a1, v8s& hi, v8s& lo) {
    unsigned h0 = cvt_pk(a0[0], a0[1]);
    unsigned h1 = cvt_pk(a0[2], a0[3]);
    unsigned h2 = cvt_pk(a1[0], a1[1]);
    unsigned h3 = cvt_pk(a1[2], a1[3]);
    float l0 = a0[0] - __builtin_bit_cast(float, h0 << 16);
    float l1 = a0[1] - __builtin_bit_cast(float, h0 & 0xffff0000u);
    float l2 = a0[2] - __builtin_bit_cast(float, h1 << 16);
    float l3 = a0[3] - __builtin_bit_cast(float, h1 & 0xffff0000u);
    float l4 = a1[0] - __builtin_bit_cast(float, h2 << 16);
    float l5 = a1[1] - __builtin_bit_cast(float, h2 & 0xffff0000u);
    float l6 = a1[2] - __builtin_bit_cast(float, h3 << 16);
    float l7 = a1[3] - __builtin_bit_cast(float, h3 & 0xffff0000u);
    unsigned q0 = cvt_pk(l0, l1);
    unsigned q1 = cvt_pk(l2, l3);
    unsigned q2 = cvt_pk(l4, l5);
    unsigned q3 = cvt_pk(l6, l7);
    hi = __builtin_bit_cast(v8s, (u32x4){h0, h1, h2, h3});
    lo = __builtin_bit_cast(v8s, (u32x4){q0, q1, q2, q3});
}

// ===========================================================================
// Weight prep (VERBATIM round-3, proven): fp32 W -> frag-ordered bf16 hi/lo.
// Per step (shorts): L0 hi@0 lo@8192 | L1 hi@16384 lo@32768 | L2 hi@49152
// lo@65536 | L3 hi@81920 lo@92160.  Step stride 102400 shorts.
// Element e: e = ((kc*NT + nt)*64 + lane)*8 + j ;
//   k = kc*32 + (lane>>4)*8 + j , n = nt*16 + (lane&15); zero-padded.
// ===========================================================================
__global__ void prep_w(const float* __restrict__ W0, const float* __restrict__ W1,
                       const float* __restrict__ W2, const float* __restrict__ W3,
                       short* __restrict__ ws)
{
    int g = blockIdx.x * 256 + threadIdx.x;
    if (g >= TSTEPS * 51200) return;
    int t = g / 51200;
    int r = g % 51200;

    int base_e, elems, NT, Kreal, Nreal;
    const float* W;
    if (r < 8192)       { base_e = 0;     elems = 8192;  NT = 8; Kreal = 48;  Nreal = 128; W = W0 + (size_t)t * DCOND * HID; }
    else if (r < 24576) { base_e = 8192;  elems = 16384; NT = 8; Kreal = 128; Nreal = 128; W = W1 + (size_t)t * HID * HID; }
    else if (r < 40960) { base_e = 24576; elems = 16384; NT = 8; Kreal = 128; Nreal = 128; W = W2 + (size_t)t * HID * HID; }
    else                { base_e = 40960; elems = 10240; NT = 5; Kreal = 128; Nreal = 73;  W = W3 + (size_t)t * HID * NPAR; }

    int e  = r - base_e;
    int j  = e & 7;
    int ln = (e >> 3) & 63;
    int q  = e >> 9;               // kc*NT + nt
    int nt = q % NT, kc = q / NT;
    int k  = kc * 32 + (ln >> 4) * 8 + j;
    int n  = nt * 16 + (ln & 15);

    float v = 0.0f;
    if (k < Kreal && n < Nreal) v = W[(size_t)k * Nreal + n];
    short hi = f2bf(v);
    short lo = f2bf(v - bf2f(hi));

    size_t o = (size_t)t * 102400 + 2 * (size_t)base_e + e;
    ws[o]         = hi;
    ws[o + elems] = lo;
}

// ===========================================================================
// Main fused kernel: 128 samples/block, 512 threads (8 waves, wave-private
// 16-row m-tile). H fp32 [128][128] LDS, 16B XOR swizzle (row&7). W hi/lo
// bf16, frag-linear, reg-staged double-buffer (T14: issue early, flush late).
// ===========================================================================
#define MBLK 128
#define NTHR 512

template<int ROUNDS>
__device__ __forceinline__ void w_issue(const short* __restrict__ g, int tid, v8s (&r)[8]) {
    #pragma unroll
    for (int i = 0; i < ROUNDS; ++i)
        r[i] = *(const v8s*)(g + tid * 8 + i * 4096);
}
template<int ROUNDS>
__device__ __forceinline__ void w_flush(short* __restrict__ lds, int tid, const v8s (&r)[8]) {
    #pragma unroll
    for (int i = 0; i < ROUNDS; ++i)
        *(v8s*)(lds + tid * 8 + i * 4096) = r[i];
}

// A from fp32 H (split on read via cvt_pk) or from pre-split ctx registers.
template<int KC, int NT, int ELEMS, bool ACT, bool AREG>
__device__ __forceinline__ void layer_run(const float* __restrict__ bias, int nreal,
                                          float* __restrict__ Hlds,
                                          const short* __restrict__ Wb,
                                          int lane, int wave,
                                          const v8s* cxh, const v8s* cxl)
{
    const int arow = wave * 16 + (lane & 15);
    const int asw  = (arow & 7) << 4;
    const int kg   = (lane >> 4) * 8;

    v8s ah[KC], al[KC];
    if (AREG) {
        #pragma unroll
        for (int kc = 0; kc < KC; ++kc) { ah[kc] = cxh[kc]; al[kc] = cxl[kc]; }
    } else {
        #pragma unroll
        for (int kc = 0; kc < KC; ++kc) {
            const int kb = (kc * 32 + kg) * 4;
            f32x4 a0 = *(const f32x4*)((const char*)Hlds + arow * 512 + (kb ^ asw));
            f32x4 a1 = *(const f32x4*)((const char*)Hlds + arow * 512 + ((kb + 16) ^ asw));
            split8(a0, a1, ah[kc], al[kc]);
        }
    }

    const int crow0 = wave * 16 + (lane >> 4) * 4;
    const int ncol  = lane & 15;

    #pragma unroll
    for (int np = 0; np < NT / 2; ++np) {
        const int nt0 = np * 2, nt1 = np * 2 + 1;
        const int n0 = nt0 * 16 + ncol, n1 = nt1 * 16 + ncol;
        const float bv0 = (n0 < nreal) ? bias[n0] : 0.0f;
        const float bv1 = (n1 < nreal) ? bias[n1] : 0.0f;
        f32x4 acc0 = {bv0, bv0, bv0, bv0};
        f32x4 acc1 = {bv1, bv1, bv1, bv1};
        #pragma unroll
        for (int kc = 0; kc < KC; ++kc) {
            const short* bp0 = Wb + ((size_t)(kc * NT + nt0) * 64 + lane) * 8;
            const short* bp1 = Wb + ((size_t)(kc * NT + nt1) * 64 + lane) * 8;
            v8s bh0 = *(const v8s*)bp0;
            v8s bl0 = *(const v8s*)(bp0 + ELEMS);
            v8s bh1 = *(const v8s*)bp1;
            v8s bl1 = *(const v8s*)(bp1 + ELEMS);
            acc0 = __builtin_amdgcn_mfma_f32_16x16x32_bf16(ah[kc], bh0, acc0, 0, 0, 0);
            acc1 = __builtin_amdgcn_mfma_f32_16x16x32_bf16(ah[kc], bh1, acc1, 0, 0, 0);
            acc0 = __builtin_amdgcn_mfma_f32_16x16x32_bf16(ah[kc], bl0, acc0, 0, 0, 0);
            acc1 = __builtin_amdgcn_mfma_f32_16x16x32_bf16(ah[kc], bl1, acc1, 0, 0, 0);
            acc0 = __builtin_amdgcn_mfma_f32_16x16x32_bf16(al[kc], bh0, acc0, 0, 0, 0);
            acc1 = __builtin_amdgcn_mfma_f32_16x16x32_bf16(al[kc], bh1, acc1, 0, 0, 0);
        }
        #pragma unroll
        for (int r = 0; r < 4; ++r) {
            const int row = crow0 + r;
            const int sw  = (row & 7) << 4;
            float v0 = acc0[r], v1 = acc1[r];
            if (ACT) { v0 = silu_f(v0); v1 = silu_f(v1); }
            *(float*)((char*)Hlds + row * 512 + ((n0 * 4) ^ sw)) = v0;
            *(float*)((char*)Hlds + row * 512 + ((n1 * 4) ^ sw)) = v1;
        }
    }
    if (NT & 1) {   // odd tail (L3: NT=5)
        const int nt = NT - 1;
        const int n0 = nt * 16 + ncol;
        const float bv0 = (n0 < nreal) ? bias[n0] : 0.0f;
        f32x4 acc0 = {bv0, bv0, bv0, bv0};
        #pragma unroll
        for (int kc = 0; kc < KC; ++kc) {
            const short* bp0 = Wb + ((size_t)(kc * NT + nt) * 64 + lane) * 8;
            v8s bh0 = *(const v8s*)bp0;
            v8s bl0 = *(const v8s*)(bp0 + ELEMS);
            acc0 = __builtin_amdgcn_mfma_f32_16x16x32_bf16(ah[kc], bh0, acc0, 0, 0, 0);
            acc0 = __builtin_amdgcn_mfma_f32_16x16x32_bf16(ah[kc], bl0, acc0, 0, 0, 0);
            acc0 = __builtin_amdgcn_mfma_f32_16x16x32_bf16(al[kc], bh0, acc0, 0, 0, 0);
        }
        #pragma unroll
        for (int r = 0; r < 4; ++r) {
            const int row = crow0 + r;
            const int sw  = (row & 7) << 4;
            float v0 = acc0[r];
            if (ACT) v0 = silu_f(v0);
            *(float*)((char*)Hlds + row * 512 + ((n0 * 4) ^ sw)) = v0;
        }
    }
}

__global__ __launch_bounds__(NTHR, 2)
void nsf_mfma(const float* __restrict__ z_g, const float* __restrict__ ctx_g,
              const float* __restrict__ b0g, const float* __restrict__ b1g,
              const float* __restrict__ b2g, const float* __restrict__ b3g,
              const float* __restrict__ locp, const float* __restrict__ sclp,
              const short* __restrict__ wsW, float* __restrict__ out, int B)
{
    __shared__ float Hlds[MBLK * 128];   // 64 KB fp32, (row&7)<<4 XOR swizzle
    __shared__ short Wlds[32768];        // 64 KB: one layer's [hi|lo]
    const int tid  = threadIdx.x;
    const int lane = tid & 63, wave = tid >> 6;
    const int blk  = blockIdx.x;

    v8s wreg[8];
    w_issue<4>(wsW, tid, wreg);          // L0(t=0) weights in flight

    // ---- ctx A-frags: load + hi/lo split ONCE into persistent registers.
    // Wave-private rows; k padded 48->64 with zeros (prep_w pads W the same).
    v8s cxh[2], cxl[2];
    {
        const int arow = wave * 16 + (lane & 15);
        int gidr = blk * MBLK + arow;
        if (gidr > B - 1) gidr = B - 1;
        const int k0 = (lane >> 4) * 8;
        const float* cg = ctx_g + (size_t)gidr * DCOND;
        f32x4 c0 = *(const f32x4*)(cg + k0);        // k0 in {0,8,16,24}
        f32x4 c1 = *(const f32x4*)(cg + k0 + 4);
        split8(c0, c1, cxh[0], cxl[0]);
        if ((lane >> 4) < 2) {                       // k = 32+k0 .. 39+k0 (<48)
            f32x4 c2 = *(const f32x4*)(cg + 32 + k0);
            f32x4 c3 = *(const f32x4*)(cg + 36 + k0);
            split8(c2, c3, cxh[1], cxl[1]);
        } else {                                     // k >= 48: zero pad
            #pragma unroll
            for (int u = 0; u < 8; ++u) { cxh[1][u] = 0; cxl[1][u] = 0; }
        }
    }

    float x = 0.0f, ld = 0.0f;
    if (lane < 16) {
        int gid = blk * MBLK + wave * 16 + lane;
        if (gid > B - 1) gid = B - 1;
        x = z_g[gid];
    }

    #pragma unroll 1
    for (int t = 0; t < TSTEPS; ++t) {
        const short* wstep = wsW + (size_t)t * 102400;
        const short* wnext = wsW + (size_t)((t + 1) % TSTEPS) * 102400;

        w_flush<4>(Wlds, tid, wreg);                 // publish W-L0 (hi|lo)
        w_issue<8>(wstep + 16384, tid, wreg);        // L1 in flight
        __syncthreads();                             // [A]

        layer_run<2, 8, 8192, true, true>(b0g + t * HID, HID, Hlds, Wlds,
                                          lane, wave, cxh, cxl);
        __syncthreads();                             // [B] L0 W-reads done

        w_flush<8>(Wlds, tid, wreg);
        w_issue<8>(wstep + 49152, tid, wreg);        // L2 in flight
        __syncthreads();                             // [C]

        layer_run<4, 8, 16384, true, false>(b1g + t * HID, HID, Hlds, Wlds,
                                            lane, wave, nullptr, nullptr);
        __syncthreads();                             // [D]

        w_flush<8>(Wlds, tid, wreg);
        w_issue<5>(wstep + 81920, tid, wreg);        // L3 in flight
        __syncthreads();                             // [E]

        layer_run<4, 8, 16384, true, false>(b2g + t * HID, HID, Hlds, Wlds,
                                            lane, wave, nullptr, nullptr);
        __syncthreads();                             // [F]

        w_flush<5>(Wlds, tid, wreg);
        w_issue<4>(wnext, tid, wreg);                // next step's L0
        __syncthreads();                             // [G]

        layer_run<4, 5, 10240, false, false>(b3g + t * NPAR, NPAR, Hlds, Wlds,
                                             lane, wave, nullptr, nullptr);

        // ---- spline: wave-local (lane L handles row wave*16+L) -> runs
        // BEFORE [H], overlapping other waves' L3 tails. All H deps same-wave.
        if (lane < 16) {
            const int rowS = wave * 16 + lane;
            const char* hrow = (const char*)Hlds + rowS * 512;
            const int sw = (rowS & 7) << 4;

            float pw[KBINS], ph[KBINS];
            #pragma unroll
            for (int g = 0; g < 6; ++g) {
                f32x4 vw = *(const f32x4*)(hrow + ((g * 16) ^ sw));
                f32x4 vh = *(const f32x4*)(hrow + (((g + 6) * 16) ^ sw));
                #pragma unroll
                for (int u = 0; u < 4; ++u) { pw[g * 4 + u] = vw[u]; ph[g * 4 + u] = vh[u]; }
            }
            float mw = pw[0], mh = ph[0];
            #pragma unroll
            for (int i = 1; i < KBINS; ++i) { mw = fmaxf(mw, pw[i]); mh = fmaxf(mh, ph[i]); }
            float wsum = 0.0f, hsum = 0.0f;
            #pragma unroll
            for (int i = 0; i < KBINS; ++i) {
                pw[i] = __expf(pw[i] - mw); wsum += pw[i];
                ph[i] = __expf(ph[i] - mh); hsum += ph[i];
            }
            const float wmul = __fdividef(2.0f * TAILF, wsum);
            const float hmul = __fdividef(2.0f * TAILF, hsum);

            // reference semantics: cw[0]=-TAIL, cw[i>=1]=RAW cumsum (no shift)
            float cw = 0.0f, ch = 0.0f;
            float cwk = -TAILF, chk = -TAILF;
            float wk = pw[0] * wmul, hk = ph[0] * hmul;
            int idx = 0;
            #pragma unroll
            for (int i = 1; i < KBINS; ++i) {
                cw += pw[i - 1] * wmul;
                ch += ph[i - 1] * hmul;
                if (cw < x) {
                    cwk = cw; chk = ch;
                    wk = pw[i] * wmul; hk = ph[i] * hmul;
                    idx = i;
                }
            }
            // derivative logits gathered at the selected bin only (cols 48..72)
            float d0 = *(const float*)(hrow + (((2 * KBINS + idx) * 4) ^ sw));
            float d1 = *(const float*)(hrow + (((2 * KBINS + idx + 1) * 4) ^ sw));
            const float dk  = fmaxf(d0, 0.0f) + __logf(1.0f + __expf(-fabsf(d0))) + 0.001f;
            const float dk1 = fmaxf(d1, 0.0f) + __logf(1.0f + __expf(-fabsf(d1))) + 0.001f;

            const bool inside = (x >= -TAILF) && (x <= TAILF);
            const float sr = __fdividef(hk, wk);
            float xi = __fdividef(x - cwk, wk);
            xi = fminf(fmaxf(xi, 1e-6f), 1.0f - 1e-6f);
            const float om  = 1.0f - xi;
            const float xio = xi * om;
            const float numer = hk * (sr * xi * xi + dk * xio);
            const float denom = sr + (dk + dk1 - 2.0f * sr) * xio;
            const float y = chk + __fdividef(numer, denom);
            const float dyd = __fdividef(sr * sr * (dk1 * xi * xi + 2.0f * sr * xio + dk * om * om),
                                         denom * denom);
            const float lg = __logf(fmaxf(dyd, 1e-10f)) + __logf(fmaxf(hk, 1e-10f))
                           - __logf(fmaxf(wk, 1e-10f));
            x  = inside ? y : x;
            ld += inside ? lg : 0.0f;
        }
        __syncthreads();                             // [H] all L3 W-reads done
    }

    if (lane < 16) {
        const int gid = blk * MBLK + wave * 16 + lane;
        if (gid < B) {
            const float s = fmaxf(sclp[0], 0.1f);
            out[gid]     = fmaf(x, s, locp[0]);
            out[B + gid] = ld;
        }
    }
}

// ===========================================================================
// Fallback (proven round-2 fp32 kernel) if ws is too small for weight prep
// ===========================================================================
#define FBLK 256
template<int KIN, int WS, int NOUT, bool ACT>
__device__ __forceinline__ void dense_chunk(const float* __restrict__ W,
                                            const float* __restrict__ bias,
                                            int j0, const float (&hin)[KIN],
                                            float* __restrict__ sb, int tid)
{
    #pragma unroll 1
    for (int jj = 0; jj < NOUT; jj += 8) {
        const int j = j0 + jj;
        float a[8];
        #pragma unroll
        for (int u = 0; u < 8; ++u) a[u] = bias[j + u];
        #pragma unroll
        for (int k = 0; k < KIN; ++k) {
            const float* w = W + k * WS + j;
            const float hk = hin[k];
            #pragma unroll
            for (int u = 0; u < 8; ++u) a[u] = fmaf(hk, w[u], a[u]);
        }
        #pragma unroll
        for (int u = 0; u < 8; ++u) {
            float v = ACT ? silu_f(a[u]) : a[u];
            sb[(jj + u) * FBLK + tid] = v;
        }
    }
}

__global__ __launch_bounds__(FBLK, 2)
void nsf_fwd_slow(const float* __restrict__ z_g, const float* __restrict__ ctx_g,
                  const float* __restrict__ W0g, const float* __restrict__ b0g,
                  const float* __restrict__ W1g, const float* __restrict__ b1g,
                  const float* __restrict__ W2g, const float* __restrict__ b2g,
                  const float* __restrict__ W3g, const float* __restrict__ b3g,
                  const float* __restrict__ locp, const float* __restrict__ sclp,
                  float* __restrict__ out, int B)
{
    __shared__ float sbuf[64 * FBLK];
    const int tid = threadIdx.x;
    const int gid = blockIdx.x * FBLK + tid;
    if (gid >= B) return;
    float x = z_g[gid], ld = 0.0f;
    #pragma unroll 1
    for (int t = 0; t < TSTEPS; ++t) {
        asm volatile("" ::: "memory");
        const float* W0 = W0g + (size_t)t * DCOND * HID;
        const float* b0 = b0g + (size_t)t * HID;
        const float* W1 = W1g + (size_t)t * HID * HID;
        const float* b1 = b1g + (size_t)t * HID;
        const float* W2 = W2g + (size_t)t * HID * HID;
        const float* b2 = b2g + (size_t)t * HID;
        const float* W3 = W3g + (size_t)t * HID * NPAR;
        const float* b3 = b3g + (size_t)t * NPAR;
        float ctx[DCOND];
        #pragma unroll
        for (int k = 0; k < DCOND; ++k) ctx[k] = ctx_g[(size_t)gid * DCOND + k];
        float h[HID];
        dense_chunk<DCOND, HID, 64, true>(W0, b0, 0, ctx, sbuf, tid);
        #pragma unroll
        for (int j = 0; j < 64; ++j) h[j] = sbuf[j * FBLK + tid];
        dense_chunk<DCOND, HID, 64, true>(W0, b0, 64, ctx, sbuf, tid);
        #pragma unroll
        for (int j = 0; j < 64; ++j) h[64 + j] = sbuf[j * FBLK + tid];
        #pragma unroll 1
        for (int l = 0; l < 2; ++l) {
            const float* W  = (l == 0) ? W1 : W2;
            const float* bb = (l == 0) ? b1 : b2;
            float hlo[64];
            dense_chunk<HID, HID, 64, true>(W, bb, 0, h, sbuf, tid);
            #pragma unroll
            for (int j = 0; j < 64; ++j) hlo[j] = sbuf[j * FBLK + tid];
            dense_chunk<HID, HID, 64, true>(W, bb, 64, h, sbuf, tid);
            #pragma unroll
            for (int j = 0; j < 64; ++j) h[64 + j] = sbuf[j * FBLK + tid];
            #pragma unroll
            for (int j = 0; j < 64; ++j) h[j] = hlo[j];
        }
        float p[NPAR];
        dense_chunk<HID, NPAR, 64, false>(W3, b3, 0, h, sbuf, tid);
        #pragma unroll
        for (int j = 0; j < 64; ++j) p[j] = sbuf[j * FBLK + tid];
        dense_chunk<HID, NPAR, 8, false>(W3, b3, 64, h, sbuf, tid);
        #pragma unroll
        for (int j = 0; j < 8; ++j) p[64 + j] = sbuf[j * FBLK + tid];
        {
            float a = b3[72];
            #pragma unroll
            for (int k = 0; k < HID; ++k) a = fmaf(h[k], W3[k * NPAR + 72], a);
            p[72] = a;
        }
        float mw = p[0];
        #pragma unroll
        for (int i = 1; i < KBINS; ++i) mw = fmaxf(mw, p[i]);
        float we[KBINS]; float wsum = 0.0f;
        #pragma unroll
        for (int i = 0; i < KBINS; ++i) { we[i] = __expf(p[i] - mw); wsum += we[i]; }
        const float wmul = __fdividef(2.0f * TAILF, wsum);
        float mh = p[KBINS];
        #pragma unroll
        for (int i = 1; i < KBINS; ++i) mh = fmaxf(mh, p[KBINS + i]);
        float he[KBINS]; float hsum = 0.0f;
        #pragma unroll
        for (int i = 0; i < KBINS; ++i) { he[i] = __expf(p[KBINS + i] - mh); hsum += he[i]; }
        const float hmul = __fdividef(2.0f * TAILF, hsum);
        float dvv[KBINS + 1];
        #pragma unroll
        for (int i = 0; i <= KBINS; ++i) {
            float xd = p[2 * KBINS + i];
            dvv[i] = fmaxf(xd, 0.0f) + __logf(1.0f + __expf(-fabsf(xd))) + 0.001f;
        }
        float cw = 0.0f, ch = 0.0f, cwk = -TAILF, chk = -TAILF;
        float wk = we[0] * wmul, hk = he[0] * hmul, dk = dvv[0], dk1 = dvv[1];
        #pragma unroll
        for (int i = 1; i < KBINS; ++i) {
            cw += we[i - 1] * wmul;
            ch += he[i - 1] * hmul;
            if (cw < x) {
                cwk = cw; chk = ch;
                wk = we[i] * wmul; hk = he[i] * hmul;
                dk = dvv[i]; dk1 = dvv[i + 1];
            }
        }
        const bool inside = (x >= -TAILF) && (x <= TAILF);
        const float sr = __fdividef(hk, wk);
        float xi = __fdividef(x - cwk, wk);
        xi = fminf(fmaxf(xi, 1e-6f), 1.0f - 1e-6f);
        const float om  = 1.0f - xi;
        const float xio = xi * om;
        const float numer = hk * (sr * xi * xi + dk * xio);
        const float denom = sr + (dk + dk1 - 2.0f * sr) * xio;
        const float y = chk + __fdividef(numer, denom);
        const float dyd = __fdividef(sr * sr * (dk1 * xi * xi + 2.0f * sr * xio + dk * om * om),
                                     denom * denom);
        const float lg = __logf(fmaxf(dyd, 1e-10f)) + __logf(fmaxf(hk, 1e-10f))
                       - __logf(fmaxf(wk, 1e-10f));
        x  = inside ? y : x;
        ld += inside ? lg : 0.0f;
    }
    const float s = fmaxf(sclp[0], 0.1f);
    out[gid]     = fmaf(x, s, locp[0]);
    out[B + gid] = ld;
}

// ===========================================================================
extern "C" void kernel_launch(void* const* d_in, const int* in_sizes, int n_in,
                              void* d_out, int out_size, void* d_ws, size_t ws_size,
                              hipStream_t stream) {
    const float* z    = (const float*)d_in[0];
    const float* ctx  = (const float*)d_in[1];
    const float* W0   = (const float*)d_in[2];
    const float* b0   = (const float*)d_in[3];
    const float* W1   = (const float*)d_in[4];
    const float* b1   = (const float*)d_in[5];
    const float* W2   = (const float*)d_in[6];
    const float* b2   = (const float*)d_in[7];
    const float* W3   = (const float*)d_in[8];
    const float* b3   = (const float*)d_in[9];
    const float* loc  = (const float*)d_in[10];
    const float* scl  = (const float*)d_in[11];
    float* out = (float*)d_out;
    const int B = in_sizes[0];

    const size_t ws_need = (size_t)TSTEPS * 102400 * sizeof(short);   // 2,048,000 B
    if (ws_size < ws_need) {
        const int nblk = (B + FBLK - 1) / FBLK;
        hipLaunchKernelGGL(nsf_fwd_slow, dim3(nblk), dim3(FBLK), 0, stream,
                           z, ctx, W0, b0, W1, b1, W2, b2, W3, b3, loc, scl, out, B);
        return;
    }

    short* ws = (short*)d_ws;
    const int prep_total = TSTEPS * 51200;
    hipLaunchKernelGGL(prep_w, dim3((prep_total + 255) / 256), dim3(256), 0, stream,
                       W0, W1, W2, W3, ws);

    const int nblk = (B + MBLK - 1) / MBLK;
    hipLaunchKernelGGL(nsf_mfma, dim3(nblk), dim3(NTHR), 0, stream,
                       z, ctx, b0, b1, b2, b3, loc, scl, ws, out, B);
}